// Round 5
// baseline (302.299 us; speedup 1.0000x reference)
//
#include <hip/hip_runtime.h>
#include <math.h>

// Problem constants (B=2, L=2048, H=2048, K=H/NH=128)
#define B_ 2
#define L_ 2048
#define H_ 2048
#define KD_ 128
#define SCALE_ 0.08838834764831845f  // 128^-0.5
#define EPS_ 1e-5f
#define K2_ 4096                     // concat-K for the dual output GEMM

typedef __bf16 bf16x8 __attribute__((ext_vector_type(8)));
typedef float f32x4 __attribute__((ext_vector_type(4)));

static __device__ __forceinline__ float sigmoidf_(float z) {
    return 1.0f / (1.0f + __expf(-z));
}

static __device__ __forceinline__ unsigned short f2bf(float f) {
    unsigned int u = __float_as_uint(f);
    unsigned int r = (u + 0x7fffu + ((u >> 16) & 1u)) >> 16;
    return (unsigned short)r;
}

static __device__ __forceinline__ float bf2f(unsigned short s) {
    return __uint_as_float(((unsigned int)s) << 16);
}

// async global->LDS, 16B per lane; lds base must be wave-uniform
#define ASYNC_COPY16(gsrc, ldst)                                             \
    __builtin_amdgcn_global_load_lds(                                        \
        (const __attribute__((address_space(1))) unsigned int*)(gsrc),       \
        (__attribute__((address_space(3))) unsigned int*)(ldst), 16, 0, 0)

// ---------------------------------------------------------------------------
// Kernel 0a: cast x -> bf16 into the x-half of Abuf (cols 2048..4095).
// (also the A-operand for the qk projection GEMM and the V source)
// ---------------------------------------------------------------------------
__global__ __launch_bounds__(256) void cast_x_half(
    const float* __restrict__ x, unsigned short* __restrict__ Abuf)
{
    size_t i = (size_t)blockIdx.x * 256 + threadIdx.x;   // group of 8 floats
    size_t m = i >> 8;
    size_t c8 = (i & 255) * 8;
    float4 v0 = *(const float4*)(x + m * H_ + c8);
    float4 v1 = *(const float4*)(x + m * H_ + c8 + 4);
    ushort4 a, b;
    a.x = f2bf(v0.x); a.y = f2bf(v0.y); a.z = f2bf(v0.z); a.w = f2bf(v0.w);
    b.x = f2bf(v1.x); b.y = f2bf(v1.y); b.z = f2bf(v1.z); b.w = f2bf(v1.w);
    unsigned short* dst = Abuf + m * K2_ + H_ + c8;
    *(ushort4*)dst = a;
    *(ushort4*)(dst + 4) = b;
}

// Kernel 0b: cast [Wq | Wk] -> bf16 [256][2048]; also zero the rrms accum.
__global__ __launch_bounds__(256) void cast_Wqk(
    const float* __restrict__ Wq, const float* __restrict__ Wk,
    unsigned short* __restrict__ Wqk, float* __restrict__ rrms_acc)
{
    size_t i = (size_t)blockIdx.x * 256 + threadIdx.x;   // group of 8 floats
    if (i < 4096) rrms_acc[i] = 0.f;
    const size_t half = (size_t)KD_ * H_ / 8;            // 32768 groups per W
    const float* src = (i < half) ? Wq : Wk;
    size_t j = (i < half) ? i : i - half;
    float4 v0 = *(const float4*)(src + j * 8);
    float4 v1 = *(const float4*)(src + j * 8 + 4);
    ushort4 a, b;
    a.x = f2bf(v0.x); a.y = f2bf(v0.y); a.z = f2bf(v0.z); a.w = f2bf(v0.w);
    b.x = f2bf(v1.x); b.y = f2bf(v1.y); b.z = f2bf(v1.z); b.w = f2bf(v1.w);
    unsigned short* dst = Wqk + i * 8;
    *(ushort4*)dst = a;
    *(ushort4*)(dst + 4) = b;
}

// ---------------------------------------------------------------------------
// Kernel 1: qk projection GEMM via MFMA, split-K.
// A = x bf16 (Abuf x-half, row stride K2_), B = Wqk [256][2048] bf16.
// M=4096, N=256, K=2048 split into 4 slices of 512. Partials fp32 [4][4096][256].
// ---------------------------------------------------------------------------
__global__ __launch_bounds__(256) void qk_proj_mfma(
    const unsigned short* __restrict__ Abuf,
    const unsigned short* __restrict__ Wqk,
    float* __restrict__ partial)
{
    __shared__ alignas(16) unsigned short As[128 * 64];
    __shared__ alignas(16) unsigned short Bs[128 * 64];
    const int tid  = threadIdx.x;
    const int wave = tid >> 6;
    const int lane = tid & 63;
    const int m0 = blockIdx.x * 128;
    const int n0 = blockIdx.y * 128;
    const int kz = blockIdx.z * 512;
    const int wm = (wave >> 1) * 64;
    const int wn = (wave & 1) * 64;

    f32x4 acc[4][4] = {};

    const int se  = lane * 8;
    const int ldsbase = (wave * 4) * 512;
    const int frow = lane & 15;
    const int fk   = (lane >> 4) * 8;

    for (int k0 = kz; k0 < kz + 512; k0 += 64) {
        #pragma unroll
        for (int it = 0; it < 4; ++it) {
            int e = ldsbase + it * 512 + se;
            int r = e >> 6, cc = e & 63;
            const unsigned short* ga =
                Abuf + (size_t)(m0 + r) * K2_ + H_ + k0 + cc;
            ASYNC_COPY16(ga, &As[e]);
            const unsigned short* gb = Wqk + (size_t)(n0 + r) * H_ + k0 + cc;
            ASYNC_COPY16(gb, &Bs[e]);
        }
        __syncthreads();
        #pragma unroll
        for (int ksub = 0; ksub < 2; ++ksub) {
            bf16x8 af[4], bf[4];
            #pragma unroll
            for (int i = 0; i < 4; ++i)
                af[i] = *(const bf16x8*)(As + (wm + i * 16 + frow) * 64 + ksub * 32 + fk);
            #pragma unroll
            for (int j = 0; j < 4; ++j)
                bf[j] = *(const bf16x8*)(Bs + (wn + j * 16 + frow) * 64 + ksub * 32 + fk);
            #pragma unroll
            for (int i = 0; i < 4; ++i)
                #pragma unroll
                for (int j = 0; j < 4; ++j)
                    acc[i][j] = __builtin_amdgcn_mfma_f32_16x16x32_bf16(
                        af[i], bf[j], acc[i][j], 0, 0, 0);
        }
        __syncthreads();
    }

    float* pz = partial + (size_t)blockIdx.z * 4096 * 256;
    #pragma unroll
    for (int i = 0; i < 4; ++i) {
        #pragma unroll
        for (int reg = 0; reg < 4; ++reg) {
            int m = m0 + wm + i * 16 + (lane >> 4) * 4 + reg;
            #pragma unroll
            for (int j = 0; j < 4; ++j) {
                int n = n0 + wn + j * 16 + (lane & 15);
                pz[(size_t)m * 256 + n] = acc[i][j][reg];
            }
        }
    }
}

// ---------------------------------------------------------------------------
// Kernel 2 (fused): split-K reduce + epilogue + chunk-local gate scan +
// chunk-referenced bf16 scaling. No global prefix sum needed: all scale
// factors are within-chunk sums:
//   qt = q * exp(S_t)        S_t = sum_{chunk start..t} g  (inclusive)
//   kA = ks * exp(-S_t)
//   kB = ks * exp(T - S_t)   T = full-chunk sum (<=0, so kB <= ks)
// where q = silu(xWq^T)*SCALE, ks = sigmoid(xWk^T), g = -log1p(exp(ks)).
// Block = (chunk c, batch b); 256 thr = (kd 0..127) x (half 0..1, 32 rows).
// ---------------------------------------------------------------------------
__global__ __launch_bounds__(256) void scan_scale_kernel(
    const float* __restrict__ partial,
    unsigned short* __restrict__ qt_b, unsigned short* __restrict__ kA_b,
    unsigned short* __restrict__ kB_b)
{
    const int c = blockIdx.x, b = blockIdx.y;
    const int tid = threadIdx.x;
    const int kd = tid & 127;
    const int h = tid >> 7;
    const size_t stride = (size_t)4096 * 256;
    const int row0 = b * L_ + c * 64 + h * 32;

    float qv[32], kv[32], gp[32];
    float run = 0.f;
    #pragma unroll
    for (int j = 0; j < 32; ++j) {
        size_t off = (size_t)(row0 + j) * 256;
        float sq = partial[off + kd] + partial[stride + off + kd]
                 + partial[2 * stride + off + kd] + partial[3 * stride + off + kd];
        float sk = partial[off + 128 + kd] + partial[stride + off + 128 + kd]
                 + partial[2 * stride + off + 128 + kd]
                 + partial[3 * stride + off + 128 + kd];
        float ksv = sigmoidf_(sk);
        qv[j] = sq * sigmoidf_(sq) * SCALE_;
        kv[j] = ksv;
        run += -log1pf(__expf(ksv));   // g_t, in (-1.3133, -0.6931)
        gp[j] = run;
    }
    __shared__ float s_half[2][128];
    s_half[h][kd] = run;
    __syncthreads();
    const float base = h ? s_half[0][kd] : 0.f;
    const float total = s_half[0][kd] + s_half[1][kd];
    #pragma unroll
    for (int j = 0; j < 32; ++j) {
        float s = base + gp[j];        // in [-84.05, -0.69]: exp stays in range
        size_t idx = (size_t)(row0 + j) * KD_ + kd;
        qt_b[idx] = f2bf(qv[j] * __expf(s));
        kA_b[idx] = f2bf(kv[j] * __expf(-s));
        kB_b[idx] = f2bf(kv[j] * __expf(total - s));
    }
}

// ---------------------------------------------------------------------------
// Kernel 3: banded GLA attention, all-MFMA (decay <= 0.5/step => band of 128
// suffices; truncation < 0.5^65). Writes bf16 o into Abuf o-half and
// accumulates per-row sum(o^2) into rrms_acc via atomics.
// ---------------------------------------------------------------------------
#define SV_ 130   // Vt row stride (elems)
#define SP_ 136   // Psh row stride (elems)

__global__ __launch_bounds__(256) void gla_attn_mfma(
    const unsigned short* __restrict__ qt_b,
    const unsigned short* __restrict__ kA_b,
    const unsigned short* __restrict__ kB_b,
    unsigned short* Abuf,          // reads x-half (cols 2048+), writes o-half
    float* __restrict__ rrms_acc)
{
    const int c  = blockIdx.x;   // chunk 0..31
    const int b  = blockIdx.y;
    const int vt = blockIdx.z;   // 0..15
    const int tid = threadIdx.x;
    const int w = tid >> 6, l = tid & 63;
    const int lr = l & 15, lq = l >> 4;
    const int q0 = c * 64, kpos0 = q0 - 64, v0c = vt * 128;
    const size_t rowbase = (size_t)b * L_;

    __shared__ alignas(16) unsigned short Vt[128 * SV_];
    __shared__ alignas(16) unsigned short Psh[64 * SP_];

    // ---- stage V transposed: Vt[vcol][key] ----
    {
        const int a = tid & 15;       // col group (8 cols)
        const int kr0 = tid >> 4;
        for (int kr = kr0; kr < 128; kr += 16) {
            int kp = kpos0 + kr;
            ushort4 u0 = {0, 0, 0, 0}, u1 = {0, 0, 0, 0};
            if (kp >= 0) {
                const unsigned short* src =
                    Abuf + (rowbase + kp) * K2_ + H_ + v0c + a * 8;
                u0 = *(const ushort4*)src;
                u1 = *(const ushort4*)(src + 4);
            }
            unsigned short vals[8] = {u0.x, u0.y, u0.z, u0.w,
                                      u1.x, u1.y, u1.z, u1.w};
            #pragma unroll
            for (int j = 0; j < 8; ++j)
                Vt[(a * 8 + j) * SV_ + kr] = vals[j];
        }
    }

    // ---- phase 1: P = qt . k~^T ----
    bf16x8 aq[4];
    {
        const unsigned short* qrow = qt_b + (rowbase + q0 + 16 * w + lr) * KD_;
        #pragma unroll
        for (int kt = 0; kt < 4; ++kt)
            aq[kt] = *(const bf16x8*)(qrow + kt * 32 + lq * 8);
    }
    #pragma unroll
    for (int jt = 0; jt < 8; ++jt) {
        f32x4 p = {};
        const int si = jt * 16 + lr;          // window key index 0..127
        const bool prev = (jt < 4);
        const bool dead = (c == 0 && prev);
        if (!dead) {
            int kp = prev ? (kpos0 + si) : (q0 + si - 64);
            const unsigned short* kb = (prev ? kB_b : kA_b) + (rowbase + kp) * KD_;
            #pragma unroll
            for (int kt = 0; kt < 4; ++kt) {
                bf16x8 bk = *(const bf16x8*)(kb + kt * 32 + lq * 8);
                p = __builtin_amdgcn_mfma_f32_16x16x32_bf16(aq[kt], bk, p, 0, 0, 0);
            }
        }
        #pragma unroll
        for (int reg = 0; reg < 4; ++reg) {
            int ti = 16 * w + lq * 4 + reg;   // q row 0..63
            bool keep = !dead && (si <= ti + 64);
            Psh[ti * SP_ + si] = keep ? f2bf(p[reg]) : (unsigned short)0;
        }
    }
    __syncthreads();

    // ---- phase 2: O = P @ V ----
    bf16x8 ap[4];
    #pragma unroll
    for (int kt = 0; kt < 4; ++kt)
        ap[kt] = *(const bf16x8*)(Psh + (16 * w + lr) * SP_ + kt * 32 + lq * 8);
    float rsum[4] = {0.f, 0.f, 0.f, 0.f};
    #pragma unroll
    for (int jt = 0; jt < 8; ++jt) {
        f32x4 oa = {};
        const int n = jt * 16 + lr;
        #pragma unroll
        for (int kt = 0; kt < 4; ++kt) {
            const unsigned int* vp =
                (const unsigned int*)(Vt + n * SV_ + kt * 32 + lq * 8);
            union { unsigned int u[4]; bf16x8 v; } bb;
            bb.u[0] = vp[0]; bb.u[1] = vp[1]; bb.u[2] = vp[2]; bb.u[3] = vp[3];
            oa = __builtin_amdgcn_mfma_f32_16x16x32_bf16(ap[kt], bb.v, oa, 0, 0, 0);
        }
        #pragma unroll
        for (int reg = 0; reg < 4; ++reg) {
            int qrow = 16 * w + lq * 4 + reg;
            size_t orow = rowbase + q0 + qrow;
            float val = oa[reg];
            Abuf[orow * K2_ + v0c + n] = f2bf(val);
            rsum[reg] += val * val;
        }
    }
    // reduce sum(o^2) over the 16 lanes sharing lq (xor of low 4 bits)
    #pragma unroll
    for (int mk = 1; mk < 16; mk <<= 1) {
        #pragma unroll
        for (int reg = 0; reg < 4; ++reg)
            rsum[reg] += __shfl_xor(rsum[reg], mk, 64);
    }
    if (lr == 0) {
        #pragma unroll
        for (int reg = 0; reg < 4; ++reg)
            atomicAdd(&rrms_acc[rowbase + q0 + 16 * w + lq * 4 + reg], rsum[reg]);
    }
}

// Kernel 4-prep: cast/concat B = [Wog | Wig] -> bf16 [2048][4096]
__global__ __launch_bounds__(256) void cast_concat_B(
    const float* __restrict__ Wog, const float* __restrict__ Wig,
    unsigned short* __restrict__ Bbuf)
{
    size_t i = (size_t)blockIdx.x * 256 + threadIdx.x;
    const size_t half = (size_t)2048 * 512;
    const float* src = (i < half) ? Wog : Wig;
    size_t j = (i < half) ? i : i - half;
    size_t n = j >> 9;
    size_t c4 = (j & 511) * 4;
    float4 v = *(const float4*)(src + n * H_ + c4);
    ushort4 bb;
    bb.x = f2bf(v.x); bb.y = f2bf(v.y); bb.z = f2bf(v.z); bb.w = f2bf(v.w);
    size_t off = (i < half) ? 0 : H_;
    *(ushort4*)(Bbuf + n * K2_ + off + c4) = bb;
}

// ---------------------------------------------------------------------------
// Kernel 4: go = A @ B^T via bf16 MFMA (m97 structure). Fused epilogue:
// rv = rsqrt(mean(o^2)+eps) from the atomic accumulator;
// out = (o*rv*gw) * go * sigmoid(go).  M=4096, N=2048, K=4096.
// ---------------------------------------------------------------------------
__global__ __launch_bounds__(256) void out_gemm_mfma(
    const unsigned short* __restrict__ Abuf,
    const unsigned short* __restrict__ Bbuf,
    const float* __restrict__ gw, const float* __restrict__ rrms_acc,
    float* __restrict__ out)
{
    __shared__ alignas(16) unsigned short As[128 * 64];
    __shared__ alignas(16) unsigned short Bs[128 * 64];
    const int tid  = threadIdx.x;
    const int wave = tid >> 6;
    const int lane = tid & 63;
    const int m0 = blockIdx.x * 128;
    const int n0 = blockIdx.y * 128;
    const int wm = (wave >> 1) * 64;
    const int wn = (wave & 1) * 64;

    f32x4 acc[4][4] = {};

    const int se  = lane * 8;
    const int ldsbase = (wave * 4) * 512;
    const int frow = lane & 15;
    const int fk   = (lane >> 4) * 8;

    for (int k0 = 0; k0 < K2_; k0 += 64) {
        #pragma unroll
        for (int it = 0; it < 4; ++it) {
            int e = ldsbase + it * 512 + se;
            int r = e >> 6, cc = e & 63;
            const unsigned short* ga = Abuf + (size_t)(m0 + r) * K2_ + k0 + cc;
            ASYNC_COPY16(ga, &As[e]);
            const unsigned short* gb = Bbuf + (size_t)(n0 + r) * K2_ + k0 + cc;
            ASYNC_COPY16(gb, &Bs[e]);
        }
        __syncthreads();
        #pragma unroll
        for (int ksub = 0; ksub < 2; ++ksub) {
            bf16x8 af[4], bf[4];
            #pragma unroll
            for (int i = 0; i < 4; ++i)
                af[i] = *(const bf16x8*)(As + (wm + i * 16 + frow) * 64 + ksub * 32 + fk);
            #pragma unroll
            for (int j = 0; j < 4; ++j)
                bf[j] = *(const bf16x8*)(Bs + (wn + j * 16 + frow) * 64 + ksub * 32 + fk);
            #pragma unroll
            for (int i = 0; i < 4; ++i)
                #pragma unroll
                for (int j = 0; j < 4; ++j)
                    acc[i][j] = __builtin_amdgcn_mfma_f32_16x16x32_bf16(
                        af[i], bf[j], acc[i][j], 0, 0, 0);
        }
        __syncthreads();
    }

    #pragma unroll
    for (int i = 0; i < 4; ++i) {
        #pragma unroll
        for (int reg = 0; reg < 4; ++reg) {
            int m = m0 + wm + i * 16 + (lane >> 4) * 4 + reg;
            float rv = rsqrtf(rrms_acc[m] * (1.0f / H_) + EPS_);
            #pragma unroll
            for (int j = 0; j < 4; ++j) {
                int n = n0 + wn + j * 16 + (lane & 15);
                float go = acc[i][j][reg];
                float ov = bf2f(Abuf[(size_t)m * K2_ + n]);   // bf16 o
                out[(size_t)m * H_ + n] = ov * rv * gw[n] * go * sigmoidf_(go);
            }
        }
    }
}

// ---------------------------------------------------------------------------
extern "C" void kernel_launch(void* const* d_in, const int* in_sizes, int n_in,
                              void* d_out, int out_size, void* d_ws, size_t ws_size,
                              hipStream_t stream) {
    (void)in_sizes; (void)n_in; (void)out_size; (void)ws_size;
    const float* x   = (const float*)d_in[0];
    const float* Wq  = (const float*)d_in[1];
    const float* Wk  = (const float*)d_in[2];
    const float* Wog = (const float*)d_in[3];
    const float* Wig = (const float*)d_in[4];
    const float* gw  = (const float*)d_in[5];
    float* out = (float*)d_out;

    const size_t MK = (size_t)B_ * L_ * KD_;               // 524288
    unsigned short* Abuf = (unsigned short*)d_ws;          // [4096][4096] bf16
    unsigned short* Bbuf = Abuf + (size_t)4096 * K2_;      // [2048][4096] bf16
    unsigned short* qt_b = Bbuf + (size_t)2048 * K2_;      // [4096][128] bf16
    unsigned short* kA_b = qt_b + MK;
    unsigned short* kB_b = kA_b + MK;
    unsigned short* Wqk  = kB_b + MK;                      // [256][2048] bf16
    float* partial  = (float*)(Wqk + (size_t)256 * H_);    // [4][4096][256] fp32
    float* rrms_acc = partial + (size_t)4 * 4096 * 256;    // [4096] fp32
    // ws use: 32+16 MB bf16 GEMM bufs + 3 MB qk + 1 MB W + 16 MB partial ~ 68 MB

    cast_x_half<<<4096, 256, 0, stream>>>(x, Abuf);
    cast_Wqk<<<256, 256, 0, stream>>>(Wq, Wk, Wqk, rrms_acc);
    qk_proj_mfma<<<dim3(32, 2, 4), 256, 0, stream>>>(Abuf, Wqk, partial);
    scan_scale_kernel<<<dim3(32, B_), 256, 0, stream>>>(partial, qt_b, kA_b, kB_b);
    cast_concat_B<<<8192, 256, 0, stream>>>(Wog, Wig, Bbuf);
    gla_attn_mfma<<<dim3(32, B_, 16), 256, 0, stream>>>(qt_b, kA_b, kB_b, Abuf, rrms_acc);
    out_gemm_mfma<<<dim3(32, 16), 256, 0, stream>>>(Abuf, Bbuf, gw, rrms_acc, out);
}

// Round 6
// 260.324 us; speedup vs baseline: 1.1612x; 1.1612x over previous
//
#include <hip/hip_runtime.h>
#include <math.h>

// Problem constants (B=2, L=2048, H=2048, K=H/NH=128)
#define B_ 2
#define L_ 2048
#define H_ 2048
#define KD_ 128
#define SCALE_ 0.08838834764831845f  // 128^-0.5
#define EPS_ 1e-5f
#define K2_ 4096                     // concat-K for the dual output GEMM

typedef __bf16 bf16x8 __attribute__((ext_vector_type(8)));
typedef float f32x4 __attribute__((ext_vector_type(4)));

static __device__ __forceinline__ float sigmoidf_(float z) {
    return 1.0f / (1.0f + __expf(-z));
}

static __device__ __forceinline__ unsigned short f2bf(float f) {
    unsigned int u = __float_as_uint(f);
    unsigned int r = (u + 0x7fffu + ((u >> 16) & 1u)) >> 16;
    return (unsigned short)r;
}

static __device__ __forceinline__ float bf2f(unsigned short s) {
    return __uint_as_float(((unsigned int)s) << 16);
}

// async global->LDS, 16B per lane; lds base must be wave-uniform
#define ASYNC_COPY16(gsrc, ldst)                                             \
    __builtin_amdgcn_global_load_lds(                                        \
        (const __attribute__((address_space(1))) unsigned int*)(gsrc),       \
        (__attribute__((address_space(3))) unsigned int*)(ldst), 16, 0, 0)

// ---------------------------------------------------------------------------
// Kernel 0 (merged prep): jobA cast x->bf16 (Abuf x-half) | jobB cast
// [Wq|Wk]->bf16 + zero rrms_acc | jobC cast [Wog|Wig]->bf16 (Bbuf).
// ---------------------------------------------------------------------------
#define JOBA_BLKS 4096   // 1048576 groups of 8
#define JOBB_BLKS 256    // 65536 groups
#define JOBC_BLKS 4096   // 1048576 groups

__global__ __launch_bounds__(256) void prep_all(
    const float* __restrict__ x, const float* __restrict__ Wq,
    const float* __restrict__ Wk, const float* __restrict__ Wog,
    const float* __restrict__ Wig, unsigned short* __restrict__ Abuf,
    unsigned short* __restrict__ Wqk, unsigned short* __restrict__ Bbuf,
    float* __restrict__ rrms_acc)
{
    const int blk = blockIdx.x;
    const float* src;
    unsigned short* dst;
    if (blk < JOBA_BLKS) {
        size_t i = (size_t)blk * 256 + threadIdx.x;
        size_t m = i >> 8, c8 = (i & 255) * 8;
        src = x + m * H_ + c8;
        dst = Abuf + m * K2_ + H_ + c8;
    } else if (blk < JOBA_BLKS + JOBB_BLKS) {
        size_t i = (size_t)(blk - JOBA_BLKS) * 256 + threadIdx.x;
        if (i < 4096) rrms_acc[i] = 0.f;
        const size_t half = (size_t)KD_ * H_ / 8;   // 32768
        src = ((i < half) ? Wq : Wk) + ((i < half) ? i : i - half) * 8;
        dst = Wqk + i * 8;
    } else {
        size_t i = (size_t)(blk - JOBA_BLKS - JOBB_BLKS) * 256 + threadIdx.x;
        const size_t half = (size_t)H_ * H_ / 8;    // 524288
        size_t j = (i < half) ? i : i - half;
        size_t n = j >> 8, c8 = (j & 255) * 8;
        src = ((i < half) ? Wog : Wig) + n * H_ + c8;
        dst = Bbuf + n * K2_ + ((i < half) ? 0 : H_) + c8;
    }
    float4 v0 = *(const float4*)src;
    float4 v1 = *(const float4*)(src + 4);
    ushort4 a, b;
    a.x = f2bf(v0.x); a.y = f2bf(v0.y); a.z = f2bf(v0.z); a.w = f2bf(v0.w);
    b.x = f2bf(v1.x); b.y = f2bf(v1.y); b.z = f2bf(v1.z); b.w = f2bf(v1.w);
    *(ushort4*)dst = a;
    *(ushort4*)(dst + 4) = b;
}

// ---------------------------------------------------------------------------
// Kernel 1: qk projection GEMM via MFMA, split-K, XOR-swizzled LDS.
// A = x bf16 (Abuf x-half, row stride K2_), B = Wqk [256][2048] bf16.
// M=4096, N=256, K=2048 split into 4 slices of 512. Partials fp32 [4][4096][256].
// LDS layout: As[r][c'] holds global column c' ^ ((r&7)<<3) -> within a
// 16-lane phase the 8 lane&7 values cover all 32 banks (2-way alias = free).
// ---------------------------------------------------------------------------
__global__ __launch_bounds__(256) void qk_proj_mfma(
    const unsigned short* __restrict__ Abuf,
    const unsigned short* __restrict__ Wqk,
    float* __restrict__ partial)
{
    __shared__ alignas(16) unsigned short As[128 * 64];
    __shared__ alignas(16) unsigned short Bs[128 * 64];
    const int tid  = threadIdx.x;
    const int wave = tid >> 6;
    const int lane = tid & 63;
    const int m0 = blockIdx.x * 128;
    const int n0 = blockIdx.y * 128;
    const int kz = blockIdx.z * 512;
    const int wm = (wave >> 1) * 64;
    const int wn = (wave & 1) * 64;

    f32x4 acc[4][4] = {};

    const int se  = lane * 8;
    const int ldsbase = (wave * 4) * 512;
    const int frow = lane & 15;
    const int fk   = (lane >> 4) * 8;
    const int gswz = (((lane & 7) ^ (lane >> 3)) << 3);  // staging src column
    const int rswz = ((lane & 7) << 3);                  // fragment read XOR

    for (int k0 = kz; k0 < kz + 512; k0 += 64) {
        #pragma unroll
        for (int it = 0; it < 4; ++it) {
            int e = ldsbase + it * 512 + se;
            int r = e >> 6;
            const unsigned short* ga =
                Abuf + (size_t)(m0 + r) * K2_ + H_ + k0 + gswz;
            ASYNC_COPY16(ga, &As[e]);
            const unsigned short* gb = Wqk + (size_t)(n0 + r) * H_ + k0 + gswz;
            ASYNC_COPY16(gb, &Bs[e]);
        }
        __syncthreads();
        #pragma unroll
        for (int ksub = 0; ksub < 2; ++ksub) {
            bf16x8 af[4], bf[4];
            #pragma unroll
            for (int i = 0; i < 4; ++i)
                af[i] = *(const bf16x8*)(As + (wm + i * 16 + frow) * 64 +
                                         ((ksub * 32 + fk) ^ rswz));
            #pragma unroll
            for (int j = 0; j < 4; ++j)
                bf[j] = *(const bf16x8*)(Bs + (wn + j * 16 + frow) * 64 +
                                         ((ksub * 32 + fk) ^ rswz));
            #pragma unroll
            for (int i = 0; i < 4; ++i)
                #pragma unroll
                for (int j = 0; j < 4; ++j)
                    acc[i][j] = __builtin_amdgcn_mfma_f32_16x16x32_bf16(
                        af[i], bf[j], acc[i][j], 0, 0, 0);
        }
        __syncthreads();
    }

    float* pz = partial + (size_t)blockIdx.z * 4096 * 256;
    #pragma unroll
    for (int i = 0; i < 4; ++i) {
        #pragma unroll
        for (int reg = 0; reg < 4; ++reg) {
            int m = m0 + wm + i * 16 + (lane >> 4) * 4 + reg;
            #pragma unroll
            for (int j = 0; j < 4; ++j) {
                int n = n0 + wn + j * 16 + (lane & 15);
                pz[(size_t)m * 256 + n] = acc[i][j][reg];
            }
        }
    }
}

// ---------------------------------------------------------------------------
// Kernel 2 (fused): split-K reduce + epilogue + chunk-local gate scan +
// chunk-referenced bf16 scaling.
//   qt = q * exp(S_t)   S_t = within-chunk inclusive sum of g (<= 0)
//   kA = ks * exp(-S_t)
//   kB = ks * exp(T - S_t)   T = full-chunk sum
// Grid (32 chunks, B, 4 kd-groups); 256 thr = 32 kd x 8 row-groups of 8.
// ---------------------------------------------------------------------------
__global__ __launch_bounds__(256) void scan_scale_kernel(
    const float* __restrict__ partial,
    unsigned short* __restrict__ qt_b, unsigned short* __restrict__ kA_b,
    unsigned short* __restrict__ kB_b)
{
    const int c = blockIdx.x, b = blockIdx.y;
    const int kd = blockIdx.z * 32 + (threadIdx.x & 31);
    const int rg = threadIdx.x >> 5;              // 0..7
    const size_t stride = (size_t)4096 * 256;
    const int row0 = b * L_ + c * 64 + rg * 8;

    float qv[8], kv[8], gp[8];
    float run = 0.f;
    #pragma unroll
    for (int j = 0; j < 8; ++j) {
        size_t off = (size_t)(row0 + j) * 256;
        float sq = partial[off + kd] + partial[stride + off + kd]
                 + partial[2 * stride + off + kd] + partial[3 * stride + off + kd];
        float sk = partial[off + 128 + kd] + partial[stride + off + 128 + kd]
                 + partial[2 * stride + off + 128 + kd]
                 + partial[3 * stride + off + 128 + kd];
        float ksv = sigmoidf_(sk);
        qv[j] = sq * sigmoidf_(sq) * SCALE_;
        kv[j] = ksv;
        run += -log1pf(__expf(ksv));   // g_t in (-1.3133, -0.6931)
        gp[j] = run;
    }
    __shared__ float s_seg[8][32];
    s_seg[rg][threadIdx.x & 31] = run;
    __syncthreads();
    float base = 0.f, total = 0.f;
    #pragma unroll
    for (int r = 0; r < 8; ++r) {
        float v = s_seg[r][threadIdx.x & 31];
        base += (r < rg) ? v : 0.f;
        total += v;
    }
    #pragma unroll
    for (int j = 0; j < 8; ++j) {
        float s = base + gp[j];        // in [-84.05, -0.69]: exp in fp32 range
        size_t idx = (size_t)(row0 + j) * KD_ + kd;
        qt_b[idx] = f2bf(qv[j] * __expf(s));
        kA_b[idx] = f2bf(kv[j] * __expf(-s));
        kB_b[idx] = f2bf(kv[j] * __expf(total - s));
    }
}

// ---------------------------------------------------------------------------
// Kernel 3: banded GLA attention, all-MFMA (decay <= 0.5/step => band of 128
// suffices; truncation < 0.5^65). Writes bf16 o into Abuf o-half and
// accumulates per-row sum(o^2) into rrms_acc via atomics.
// ---------------------------------------------------------------------------
#define SV_ 130   // Vt row stride (elems)
#define SP_ 136   // Psh row stride (elems)

__global__ __launch_bounds__(256) void gla_attn_mfma(
    const unsigned short* __restrict__ qt_b,
    const unsigned short* __restrict__ kA_b,
    const unsigned short* __restrict__ kB_b,
    unsigned short* Abuf,          // reads x-half (cols 2048+), writes o-half
    float* __restrict__ rrms_acc)
{
    const int c  = blockIdx.x;   // chunk 0..31
    const int b  = blockIdx.y;
    const int vt = blockIdx.z;   // 0..15
    const int tid = threadIdx.x;
    const int w = tid >> 6, l = tid & 63;
    const int lr = l & 15, lq = l >> 4;
    const int q0 = c * 64, kpos0 = q0 - 64, v0c = vt * 128;
    const size_t rowbase = (size_t)b * L_;

    __shared__ alignas(16) unsigned short Vt[128 * SV_];
    __shared__ alignas(16) unsigned short Psh[64 * SP_];

    // ---- stage V transposed: Vt[vcol][key] ----
    {
        const int a = tid & 15;       // col group (8 cols)
        const int kr0 = tid >> 4;
        for (int kr = kr0; kr < 128; kr += 16) {
            int kp = kpos0 + kr;
            ushort4 u0 = {0, 0, 0, 0}, u1 = {0, 0, 0, 0};
            if (kp >= 0) {
                const unsigned short* src =
                    Abuf + (rowbase + kp) * K2_ + H_ + v0c + a * 8;
                u0 = *(const ushort4*)src;
                u1 = *(const ushort4*)(src + 4);
            }
            unsigned short vals[8] = {u0.x, u0.y, u0.z, u0.w,
                                      u1.x, u1.y, u1.z, u1.w};
            #pragma unroll
            for (int j = 0; j < 8; ++j)
                Vt[(a * 8 + j) * SV_ + kr] = vals[j];
        }
    }

    // ---- phase 1: P = qt . k~^T ----
    bf16x8 aq[4];
    {
        const unsigned short* qrow = qt_b + (rowbase + q0 + 16 * w + lr) * KD_;
        #pragma unroll
        for (int kt = 0; kt < 4; ++kt)
            aq[kt] = *(const bf16x8*)(qrow + kt * 32 + lq * 8);
    }
    #pragma unroll
    for (int jt = 0; jt < 8; ++jt) {
        f32x4 p = {};
        const int si = jt * 16 + lr;          // window key index 0..127
        const bool prev = (jt < 4);
        const bool dead = (c == 0 && prev);
        if (!dead) {
            int kp = prev ? (kpos0 + si) : (q0 + si - 64);
            const unsigned short* kb = (prev ? kB_b : kA_b) + (rowbase + kp) * KD_;
            #pragma unroll
            for (int kt = 0; kt < 4; ++kt) {
                bf16x8 bk = *(const bf16x8*)(kb + kt * 32 + lq * 8);
                p = __builtin_amdgcn_mfma_f32_16x16x32_bf16(aq[kt], bk, p, 0, 0, 0);
            }
        }
        #pragma unroll
        for (int reg = 0; reg < 4; ++reg) {
            int ti = 16 * w + lq * 4 + reg;   // q row 0..63
            bool keep = !dead && (si <= ti + 64);
            Psh[ti * SP_ + si] = keep ? f2bf(p[reg]) : (unsigned short)0;
        }
    }
    __syncthreads();

    // ---- phase 2: O = P @ V ----
    bf16x8 ap[4];
    #pragma unroll
    for (int kt = 0; kt < 4; ++kt)
        ap[kt] = *(const bf16x8*)(Psh + (16 * w + lr) * SP_ + kt * 32 + lq * 8);
    float rsum[4] = {0.f, 0.f, 0.f, 0.f};
    #pragma unroll
    for (int jt = 0; jt < 8; ++jt) {
        f32x4 oa = {};
        const int n = jt * 16 + lr;
        #pragma unroll
        for (int kt = 0; kt < 4; ++kt) {
            const unsigned int* vp =
                (const unsigned int*)(Vt + n * SV_ + kt * 32 + lq * 8);
            union { unsigned int u[4]; bf16x8 v; } bb;
            bb.u[0] = vp[0]; bb.u[1] = vp[1]; bb.u[2] = vp[2]; bb.u[3] = vp[3];
            oa = __builtin_amdgcn_mfma_f32_16x16x32_bf16(ap[kt], bb.v, oa, 0, 0, 0);
        }
        #pragma unroll
        for (int reg = 0; reg < 4; ++reg) {
            int qrow = 16 * w + lq * 4 + reg;
            size_t orow = rowbase + q0 + qrow;
            float val = oa[reg];
            Abuf[orow * K2_ + v0c + n] = f2bf(val);
            rsum[reg] += val * val;
        }
    }
    // reduce sum(o^2) over the 16 lanes sharing lq
    #pragma unroll
    for (int mk = 1; mk < 16; mk <<= 1) {
        #pragma unroll
        for (int reg = 0; reg < 4; ++reg)
            rsum[reg] += __shfl_xor(rsum[reg], mk, 64);
    }
    if (lr == 0) {
        #pragma unroll
        for (int reg = 0; reg < 4; ++reg)
            atomicAdd(&rrms_acc[rowbase + q0 + 16 * w + lq * 4 + reg], rsum[reg]);
    }
}

// ---------------------------------------------------------------------------
// Kernel 4: go = A @ B^T via bf16 MFMA (m97 structure + XOR-swizzled LDS).
// Fused epilogue: rv = rsqrt(mean(o^2)+eps); out = (o*rv*gw)*go*sigmoid(go).
// M=4096, N=2048, K=4096.
// ---------------------------------------------------------------------------
__global__ __launch_bounds__(256) void out_gemm_mfma(
    const unsigned short* __restrict__ Abuf,
    const unsigned short* __restrict__ Bbuf,
    const float* __restrict__ gw, const float* __restrict__ rrms_acc,
    float* __restrict__ out)
{
    __shared__ alignas(16) unsigned short As[128 * 64];
    __shared__ alignas(16) unsigned short Bs[128 * 64];
    const int tid  = threadIdx.x;
    const int wave = tid >> 6;
    const int lane = tid & 63;
    const int m0 = blockIdx.x * 128;
    const int n0 = blockIdx.y * 128;
    const int wm = (wave >> 1) * 64;
    const int wn = (wave & 1) * 64;

    f32x4 acc[4][4] = {};

    const int se  = lane * 8;
    const int ldsbase = (wave * 4) * 512;
    const int frow = lane & 15;
    const int fk   = (lane >> 4) * 8;
    const int gswz = (((lane & 7) ^ (lane >> 3)) << 3);
    const int rswz = ((lane & 7) << 3);

    for (int k0 = 0; k0 < K2_; k0 += 64) {
        #pragma unroll
        for (int it = 0; it < 4; ++it) {
            int e = ldsbase + it * 512 + se;
            int r = e >> 6;
            const unsigned short* ga = Abuf + (size_t)(m0 + r) * K2_ + k0 + gswz;
            ASYNC_COPY16(ga, &As[e]);
            const unsigned short* gb = Bbuf + (size_t)(n0 + r) * K2_ + k0 + gswz;
            ASYNC_COPY16(gb, &Bs[e]);
        }
        __syncthreads();
        #pragma unroll
        for (int ksub = 0; ksub < 2; ++ksub) {
            bf16x8 af[4], bf[4];
            #pragma unroll
            for (int i = 0; i < 4; ++i)
                af[i] = *(const bf16x8*)(As + (wm + i * 16 + frow) * 64 +
                                         ((ksub * 32 + fk) ^ rswz));
            #pragma unroll
            for (int j = 0; j < 4; ++j)
                bf[j] = *(const bf16x8*)(Bs + (wn + j * 16 + frow) * 64 +
                                         ((ksub * 32 + fk) ^ rswz));
            #pragma unroll
            for (int i = 0; i < 4; ++i)
                #pragma unroll
                for (int j = 0; j < 4; ++j)
                    acc[i][j] = __builtin_amdgcn_mfma_f32_16x16x32_bf16(
                        af[i], bf[j], acc[i][j], 0, 0, 0);
        }
        __syncthreads();
    }

    #pragma unroll
    for (int i = 0; i < 4; ++i) {
        #pragma unroll
        for (int reg = 0; reg < 4; ++reg) {
            int m = m0 + wm + i * 16 + (lane >> 4) * 4 + reg;
            float rv = rsqrtf(rrms_acc[m] * (1.0f / H_) + EPS_);
            #pragma unroll
            for (int j = 0; j < 4; ++j) {
                int n = n0 + wn + j * 16 + (lane & 15);
                float go = acc[i][j][reg];
                float ov = bf2f(Abuf[(size_t)m * K2_ + n]);   // bf16 o
                out[(size_t)m * H_ + n] = ov * rv * gw[n] * go * sigmoidf_(go);
            }
        }
    }
}

// ---------------------------------------------------------------------------
extern "C" void kernel_launch(void* const* d_in, const int* in_sizes, int n_in,
                              void* d_out, int out_size, void* d_ws, size_t ws_size,
                              hipStream_t stream) {
    (void)in_sizes; (void)n_in; (void)out_size; (void)ws_size;
    const float* x   = (const float*)d_in[0];
    const float* Wq  = (const float*)d_in[1];
    const float* Wk  = (const float*)d_in[2];
    const float* Wog = (const float*)d_in[3];
    const float* Wig = (const float*)d_in[4];
    const float* gw  = (const float*)d_in[5];
    float* out = (float*)d_out;

    const size_t MK = (size_t)B_ * L_ * KD_;               // 524288
    unsigned short* Abuf = (unsigned short*)d_ws;          // [4096][4096] bf16
    unsigned short* Bbuf = Abuf + (size_t)4096 * K2_;      // [2048][4096] bf16
    unsigned short* qt_b = Bbuf + (size_t)2048 * K2_;      // [4096][128] bf16
    unsigned short* kA_b = qt_b + MK;
    unsigned short* kB_b = kA_b + MK;
    unsigned short* Wqk  = kB_b + MK;                      // [256][2048] bf16
    float* partial  = (float*)(Wqk + (size_t)256 * H_);    // [4][4096][256] fp32
    float* rrms_acc = partial + (size_t)4 * 4096 * 256;    // [4096] fp32
    // ws use: 48 MB bf16 GEMM bufs + 3 MB qk + 1 MB W + 16 MB partial ~ 68 MB

    prep_all<<<JOBA_BLKS + JOBB_BLKS + JOBC_BLKS, 256, 0, stream>>>(
        x, Wq, Wk, Wog, Wig, Abuf, Wqk, Bbuf, rrms_acc);
    qk_proj_mfma<<<dim3(32, 2, 4), 256, 0, stream>>>(Abuf, Wqk, partial);
    scan_scale_kernel<<<dim3(32, B_, 4), 256, 0, stream>>>(partial, qt_b, kA_b, kB_b);
    gla_attn_mfma<<<dim3(32, B_, 16), 256, 0, stream>>>(qt_b, kA_b, kB_b, Abuf, rrms_acc);
    out_gemm_mfma<<<dim3(32, 16), 256, 0, stream>>>(Abuf, Bbuf, gw, rrms_acc, out);
}

// Round 7
// 247.306 us; speedup vs baseline: 1.2224x; 1.0526x over previous
//
#include <hip/hip_runtime.h>
#include <math.h>

// Problem constants (B=2, L=2048, H=2048, K=H/NH=128)
#define B_ 2
#define L_ 2048
#define H_ 2048
#define KD_ 128
#define SCALE_ 0.08838834764831845f  // 128^-0.5
#define EPS_ 1e-5f
#define K2_ 4096                     // concat-K for the dual output GEMM

typedef __bf16 bf16x8 __attribute__((ext_vector_type(8)));
typedef float f32x4 __attribute__((ext_vector_type(4)));

static __device__ __forceinline__ float sigmoidf_(float z) {
    return 1.0f / (1.0f + __expf(-z));
}

static __device__ __forceinline__ unsigned short f2bf(float f) {
    unsigned int u = __float_as_uint(f);
    unsigned int r = (u + 0x7fffu + ((u >> 16) & 1u)) >> 16;
    return (unsigned short)r;
}

static __device__ __forceinline__ float bf2f(unsigned short s) {
    return __uint_as_float(((unsigned int)s) << 16);
}

// async global->LDS, 16B per lane; lds base must be wave-uniform
#define ASYNC_COPY16(gsrc, ldst)                                             \
    __builtin_amdgcn_global_load_lds(                                        \
        (const __attribute__((address_space(1))) unsigned int*)(gsrc),       \
        (__attribute__((address_space(3))) unsigned int*)(ldst), 16, 0, 0)

// ---------------------------------------------------------------------------
// Kernel 0 (merged prep): jobA cast x->bf16 (Abuf x-half) | jobB cast
// [Wq|Wk]->bf16 + zero rrms_acc | jobC cast [Wog|Wig]->bf16 (Bbuf).
// ---------------------------------------------------------------------------
#define JOBA_BLKS 4096   // 1048576 groups of 8
#define JOBB_BLKS 256    // 65536 groups
#define JOBC_BLKS 4096   // 1048576 groups

__global__ __launch_bounds__(256) void prep_all(
    const float* __restrict__ x, const float* __restrict__ Wq,
    const float* __restrict__ Wk, const float* __restrict__ Wog,
    const float* __restrict__ Wig, unsigned short* __restrict__ Abuf,
    unsigned short* __restrict__ Wqk, unsigned short* __restrict__ Bbuf,
    float* __restrict__ rrms_acc)
{
    const int blk = blockIdx.x;
    const float* src;
    unsigned short* dst;
    if (blk < JOBA_BLKS) {
        size_t i = (size_t)blk * 256 + threadIdx.x;
        size_t m = i >> 8, c8 = (i & 255) * 8;
        src = x + m * H_ + c8;
        dst = Abuf + m * K2_ + H_ + c8;
    } else if (blk < JOBA_BLKS + JOBB_BLKS) {
        size_t i = (size_t)(blk - JOBA_BLKS) * 256 + threadIdx.x;
        if (i < 4096) rrms_acc[i] = 0.f;
        const size_t half = (size_t)KD_ * H_ / 8;   // 32768
        src = ((i < half) ? Wq : Wk) + ((i < half) ? i : i - half) * 8;
        dst = Wqk + i * 8;
    } else {
        size_t i = (size_t)(blk - JOBA_BLKS - JOBB_BLKS) * 256 + threadIdx.x;
        const size_t half = (size_t)H_ * H_ / 8;    // 524288
        size_t j = (i < half) ? i : i - half;
        size_t n = j >> 8, c8 = (j & 255) * 8;
        src = ((i < half) ? Wog : Wig) + n * H_ + c8;
        dst = Bbuf + n * K2_ + ((i < half) ? 0 : H_) + c8;
    }
    float4 v0 = *(const float4*)src;
    float4 v1 = *(const float4*)(src + 4);
    ushort4 a, b;
    a.x = f2bf(v0.x); a.y = f2bf(v0.y); a.z = f2bf(v0.z); a.w = f2bf(v0.w);
    b.x = f2bf(v1.x); b.y = f2bf(v1.y); b.z = f2bf(v1.z); b.w = f2bf(v1.w);
    *(ushort4*)dst = a;
    *(ushort4*)(dst + 4) = b;
}

// ---------------------------------------------------------------------------
// Kernel 1: qk projection GEMM via MFMA, split-K, XOR-swizzled LDS.
// A = x bf16 (Abuf x-half, row stride K2_), B = Wqk [256][2048] bf16.
// M=4096, N=256, K=2048 split into 4 slices of 512. Partials fp32 [4][4096][256].
// ---------------------------------------------------------------------------
__global__ __launch_bounds__(256) void qk_proj_mfma(
    const unsigned short* __restrict__ Abuf,
    const unsigned short* __restrict__ Wqk,
    float* __restrict__ partial)
{
    __shared__ alignas(16) unsigned short As[128 * 64];
    __shared__ alignas(16) unsigned short Bs[128 * 64];
    const int tid  = threadIdx.x;
    const int wave = tid >> 6;
    const int lane = tid & 63;
    const int m0 = blockIdx.x * 128;
    const int n0 = blockIdx.y * 128;
    const int kz = blockIdx.z * 512;
    const int wm = (wave >> 1) * 64;
    const int wn = (wave & 1) * 64;

    f32x4 acc[4][4] = {};

    const int se  = lane * 8;
    const int ldsbase = (wave * 4) * 512;
    const int frow = lane & 15;
    const int fk   = (lane >> 4) * 8;
    const int gswz = (((lane & 7) ^ (lane >> 3)) << 3);  // staging src column
    const int rswz = ((lane & 7) << 3);                  // fragment read XOR

    for (int k0 = kz; k0 < kz + 512; k0 += 64) {
        #pragma unroll
        for (int it = 0; it < 4; ++it) {
            int e = ldsbase + it * 512 + se;
            int r = e >> 6;
            const unsigned short* ga =
                Abuf + (size_t)(m0 + r) * K2_ + H_ + k0 + gswz;
            ASYNC_COPY16(ga, &As[e]);
            const unsigned short* gb = Wqk + (size_t)(n0 + r) * H_ + k0 + gswz;
            ASYNC_COPY16(gb, &Bs[e]);
        }
        __syncthreads();
        #pragma unroll
        for (int ksub = 0; ksub < 2; ++ksub) {
            bf16x8 af[4], bf[4];
            #pragma unroll
            for (int i = 0; i < 4; ++i)
                af[i] = *(const bf16x8*)(As + (wm + i * 16 + frow) * 64 +
                                         ((ksub * 32 + fk) ^ rswz));
            #pragma unroll
            for (int j = 0; j < 4; ++j)
                bf[j] = *(const bf16x8*)(Bs + (wn + j * 16 + frow) * 64 +
                                         ((ksub * 32 + fk) ^ rswz));
            #pragma unroll
            for (int i = 0; i < 4; ++i)
                #pragma unroll
                for (int j = 0; j < 4; ++j)
                    acc[i][j] = __builtin_amdgcn_mfma_f32_16x16x32_bf16(
                        af[i], bf[j], acc[i][j], 0, 0, 0);
        }
        __syncthreads();
    }

    float* pz = partial + (size_t)blockIdx.z * 4096 * 256;
    #pragma unroll
    for (int i = 0; i < 4; ++i) {
        #pragma unroll
        for (int reg = 0; reg < 4; ++reg) {
            int m = m0 + wm + i * 16 + (lane >> 4) * 4 + reg;
            #pragma unroll
            for (int j = 0; j < 4; ++j) {
                int n = n0 + wn + j * 16 + (lane & 15);
                pz[(size_t)m * 256 + n] = acc[i][j][reg];
            }
        }
    }
}

// ---------------------------------------------------------------------------
// Kernel 2 (fused): split-K reduce + epilogue + chunk-local gate scan +
// chunk-referenced bf16 scaling.
//   qt = q * exp(S_t)   S_t = within-chunk inclusive sum of g (<= 0)
//   kA = ks * exp(-S_t)
//   kB = ks * exp(T - S_t)   T = full-chunk sum
// Grid (32 chunks, B, 4 kd-groups); 256 thr = 32 kd x 8 row-groups of 8.
// ---------------------------------------------------------------------------
__global__ __launch_bounds__(256) void scan_scale_kernel(
    const float* __restrict__ partial,
    unsigned short* __restrict__ qt_b, unsigned short* __restrict__ kA_b,
    unsigned short* __restrict__ kB_b)
{
    const int c = blockIdx.x, b = blockIdx.y;
    const int kd = blockIdx.z * 32 + (threadIdx.x & 31);
    const int rg = threadIdx.x >> 5;              // 0..7
    const size_t stride = (size_t)4096 * 256;
    const int row0 = b * L_ + c * 64 + rg * 8;

    float qv[8], kv[8], gp[8];
    float run = 0.f;
    #pragma unroll
    for (int j = 0; j < 8; ++j) {
        size_t off = (size_t)(row0 + j) * 256;
        float sq = partial[off + kd] + partial[stride + off + kd]
                 + partial[2 * stride + off + kd] + partial[3 * stride + off + kd];
        float sk = partial[off + 128 + kd] + partial[stride + off + 128 + kd]
                 + partial[2 * stride + off + 128 + kd]
                 + partial[3 * stride + off + 128 + kd];
        float ksv = sigmoidf_(sk);
        qv[j] = sq * sigmoidf_(sq) * SCALE_;
        kv[j] = ksv;
        run += -log1pf(__expf(ksv));   // g_t in (-1.3133, -0.6931)
        gp[j] = run;
    }
    __shared__ float s_seg[8][32];
    s_seg[rg][threadIdx.x & 31] = run;
    __syncthreads();
    float base = 0.f, total = 0.f;
    #pragma unroll
    for (int r = 0; r < 8; ++r) {
        float v = s_seg[r][threadIdx.x & 31];
        base += (r < rg) ? v : 0.f;
        total += v;
    }
    #pragma unroll
    for (int j = 0; j < 8; ++j) {
        float s = base + gp[j];        // in [-84.05, -0.69]: exp in fp32 range
        size_t idx = (size_t)(row0 + j) * KD_ + kd;
        qt_b[idx] = f2bf(qv[j] * __expf(s));
        kA_b[idx] = f2bf(kv[j] * __expf(-s));
        kB_b[idx] = f2bf(kv[j] * __expf(total - s));
    }
}

// ---------------------------------------------------------------------------
// Kernel 3a: P = qt . k~^T, computed ONCE per (chunk, batch) with causal-band
// mask; written bf16 to Pbuf[cb][64 q][128 keys]. Keys 0..63 = previous
// chunk (kB weights), keys 64..127 = intra chunk (kA weights).
// Grid (32, B), 256 threads (4 waves x 16 q-rows).
// ---------------------------------------------------------------------------
__global__ __launch_bounds__(256) void p_kernel(
    const unsigned short* __restrict__ qt_b,
    const unsigned short* __restrict__ kA_b,
    const unsigned short* __restrict__ kB_b,
    unsigned short* __restrict__ Pbuf)
{
    const int c = blockIdx.x, b = blockIdx.y;
    const int tid = threadIdx.x;
    const int w = tid >> 6, l = tid & 63;
    const int lr = l & 15, lq = l >> 4;
    const int q0 = c * 64;
    const size_t rowbase = (size_t)b * L_;

    bf16x8 aq[4];
    {
        const unsigned short* qrow = qt_b + (rowbase + q0 + 16 * w + lr) * KD_;
        #pragma unroll
        for (int kt = 0; kt < 4; ++kt)
            aq[kt] = *(const bf16x8*)(qrow + kt * 32 + lq * 8);
    }
    unsigned short* pout = Pbuf + (size_t)(b * 32 + c) * 64 * 128;
    #pragma unroll
    for (int jt = 0; jt < 8; ++jt) {
        f32x4 p = {};
        const int si = jt * 16 + lr;          // window key index 0..127
        const bool prev = (jt < 4);
        const bool dead = (c == 0 && prev);
        if (!dead) {
            int kp = prev ? (q0 - 64 + si) : (q0 + si - 64);
            const unsigned short* kb = (prev ? kB_b : kA_b) + (rowbase + kp) * KD_;
            #pragma unroll
            for (int kt = 0; kt < 4; ++kt) {
                bf16x8 bk = *(const bf16x8*)(kb + kt * 32 + lq * 8);
                p = __builtin_amdgcn_mfma_f32_16x16x32_bf16(aq[kt], bk, p, 0, 0, 0);
            }
        }
        #pragma unroll
        for (int reg = 0; reg < 4; ++reg) {
            int ti = 16 * w + lq * 4 + reg;   // q row 0..63
            bool keep = !dead && (si <= ti + 64);
            pout[ti * 128 + si] = keep ? f2bf(p[reg]) : (unsigned short)0;
        }
    }
}

// ---------------------------------------------------------------------------
// Kernel 3b: O = P @ V. Stages V transposed in LDS; P read from global
// (L2-hot, 1 MB). Writes bf16 o into Abuf o-half + rrms atomics.
// Grid (32, B, 16 v-tiles of 128).
// ---------------------------------------------------------------------------
#define SV_ 130   // Vt row stride (elems)

__global__ __launch_bounds__(256) void pv_kernel(
    const unsigned short* __restrict__ Pbuf,
    unsigned short* Abuf,          // reads x-half (cols 2048+), writes o-half
    float* __restrict__ rrms_acc)
{
    const int c  = blockIdx.x;   // chunk 0..31
    const int b  = blockIdx.y;
    const int vt = blockIdx.z;   // 0..15
    const int tid = threadIdx.x;
    const int w = tid >> 6, l = tid & 63;
    const int lr = l & 15, lq = l >> 4;
    const int q0 = c * 64, kpos0 = q0 - 64, v0c = vt * 128;
    const size_t rowbase = (size_t)b * L_;

    __shared__ alignas(16) unsigned short Vt[128 * SV_];

    // ---- stage V transposed: Vt[vcol][key] ----
    {
        const int a = tid & 15;       // col group (8 cols)
        const int kr0 = tid >> 4;
        for (int kr = kr0; kr < 128; kr += 16) {
            int kp = kpos0 + kr;
            ushort4 u0 = {0, 0, 0, 0}, u1 = {0, 0, 0, 0};
            if (kp >= 0) {
                const unsigned short* src =
                    Abuf + (rowbase + kp) * K2_ + H_ + v0c + a * 8;
                u0 = *(const ushort4*)src;
                u1 = *(const ushort4*)(src + 4);
            }
            unsigned short vals[8] = {u0.x, u0.y, u0.z, u0.w,
                                      u1.x, u1.y, u1.z, u1.w};
            #pragma unroll
            for (int j = 0; j < 8; ++j)
                Vt[(a * 8 + j) * SV_ + kr] = vals[j];
        }
    }

    // P fragments from global (independent of the LDS staging)
    bf16x8 ap[4];
    {
        const unsigned short* prow =
            Pbuf + ((size_t)(b * 32 + c) * 64 + 16 * w + lr) * 128;
        #pragma unroll
        for (int kt = 0; kt < 4; ++kt)
            ap[kt] = *(const bf16x8*)(prow + kt * 32 + lq * 8);
    }
    __syncthreads();

    float rsum[4] = {0.f, 0.f, 0.f, 0.f};
    #pragma unroll
    for (int jt = 0; jt < 8; ++jt) {
        f32x4 oa = {};
        const int n = jt * 16 + lr;
        #pragma unroll
        for (int kt = 0; kt < 4; ++kt) {
            const unsigned int* vp =
                (const unsigned int*)(Vt + n * SV_ + kt * 32 + lq * 8);
            union { unsigned int u[4]; bf16x8 v; } bb;
            bb.u[0] = vp[0]; bb.u[1] = vp[1]; bb.u[2] = vp[2]; bb.u[3] = vp[3];
            oa = __builtin_amdgcn_mfma_f32_16x16x32_bf16(ap[kt], bb.v, oa, 0, 0, 0);
        }
        #pragma unroll
        for (int reg = 0; reg < 4; ++reg) {
            int qrow = 16 * w + lq * 4 + reg;
            size_t orow = rowbase + q0 + qrow;
            float val = oa[reg];
            Abuf[orow * K2_ + v0c + n] = f2bf(val);
            rsum[reg] += val * val;
        }
    }
    // reduce sum(o^2) over the 16 lanes sharing lq
    #pragma unroll
    for (int mk = 1; mk < 16; mk <<= 1) {
        #pragma unroll
        for (int reg = 0; reg < 4; ++reg)
            rsum[reg] += __shfl_xor(rsum[reg], mk, 64);
    }
    if (lr == 0) {
        #pragma unroll
        for (int reg = 0; reg < 4; ++reg)
            atomicAdd(&rrms_acc[rowbase + q0 + 16 * w + lq * 4 + reg], rsum[reg]);
    }
}

// ---------------------------------------------------------------------------
// Kernel 4: go = A @ B^T via bf16 MFMA (m97 structure + XOR-swizzled LDS).
// Fused epilogue: rv = rsqrt(mean(o^2)+eps); out = (o*rv*gw)*go*sigmoid(go).
// M=4096, N=2048, K=4096.
// ---------------------------------------------------------------------------
__global__ __launch_bounds__(256) void out_gemm_mfma(
    const unsigned short* __restrict__ Abuf,
    const unsigned short* __restrict__ Bbuf,
    const float* __restrict__ gw, const float* __restrict__ rrms_acc,
    float* __restrict__ out)
{
    __shared__ alignas(16) unsigned short As[128 * 64];
    __shared__ alignas(16) unsigned short Bs[128 * 64];
    const int tid  = threadIdx.x;
    const int wave = tid >> 6;
    const int lane = tid & 63;
    const int m0 = blockIdx.x * 128;
    const int n0 = blockIdx.y * 128;
    const int wm = (wave >> 1) * 64;
    const int wn = (wave & 1) * 64;

    f32x4 acc[4][4] = {};

    const int se  = lane * 8;
    const int ldsbase = (wave * 4) * 512;
    const int frow = lane & 15;
    const int fk   = (lane >> 4) * 8;
    const int gswz = (((lane & 7) ^ (lane >> 3)) << 3);
    const int rswz = ((lane & 7) << 3);

    for (int k0 = 0; k0 < K2_; k0 += 64) {
        #pragma unroll
        for (int it = 0; it < 4; ++it) {
            int e = ldsbase + it * 512 + se;
            int r = e >> 6;
            const unsigned short* ga = Abuf + (size_t)(m0 + r) * K2_ + k0 + gswz;
            ASYNC_COPY16(ga, &As[e]);
            const unsigned short* gb = Bbuf + (size_t)(n0 + r) * K2_ + k0 + gswz;
            ASYNC_COPY16(gb, &Bs[e]);
        }
        __syncthreads();
        #pragma unroll
        for (int ksub = 0; ksub < 2; ++ksub) {
            bf16x8 af[4], bf[4];
            #pragma unroll
            for (int i = 0; i < 4; ++i)
                af[i] = *(const bf16x8*)(As + (wm + i * 16 + frow) * 64 +
                                         ((ksub * 32 + fk) ^ rswz));
            #pragma unroll
            for (int j = 0; j < 4; ++j)
                bf[j] = *(const bf16x8*)(Bs + (wn + j * 16 + frow) * 64 +
                                         ((ksub * 32 + fk) ^ rswz));
            #pragma unroll
            for (int i = 0; i < 4; ++i)
                #pragma unroll
                for (int j = 0; j < 4; ++j)
                    acc[i][j] = __builtin_amdgcn_mfma_f32_16x16x32_bf16(
                        af[i], bf[j], acc[i][j], 0, 0, 0);
        }
        __syncthreads();
    }

    #pragma unroll
    for (int i = 0; i < 4; ++i) {
        #pragma unroll
        for (int reg = 0; reg < 4; ++reg) {
            int m = m0 + wm + i * 16 + (lane >> 4) * 4 + reg;
            float rv = rsqrtf(rrms_acc[m] * (1.0f / H_) + EPS_);
            #pragma unroll
            for (int j = 0; j < 4; ++j) {
                int n = n0 + wn + j * 16 + (lane & 15);
                float go = acc[i][j][reg];
                float ov = bf2f(Abuf[(size_t)m * K2_ + n]);   // bf16 o
                out[(size_t)m * H_ + n] = ov * rv * gw[n] * go * sigmoidf_(go);
            }
        }
    }
}

// ---------------------------------------------------------------------------
extern "C" void kernel_launch(void* const* d_in, const int* in_sizes, int n_in,
                              void* d_out, int out_size, void* d_ws, size_t ws_size,
                              hipStream_t stream) {
    (void)in_sizes; (void)n_in; (void)out_size; (void)ws_size;
    const float* x   = (const float*)d_in[0];
    const float* Wq  = (const float*)d_in[1];
    const float* Wk  = (const float*)d_in[2];
    const float* Wog = (const float*)d_in[3];
    const float* Wig = (const float*)d_in[4];
    const float* gw  = (const float*)d_in[5];
    float* out = (float*)d_out;

    const size_t MK = (size_t)B_ * L_ * KD_;               // 524288
    unsigned short* Abuf = (unsigned short*)d_ws;          // [4096][4096] bf16
    unsigned short* Bbuf = Abuf + (size_t)4096 * K2_;      // [2048][4096] bf16
    unsigned short* qt_b = Bbuf + (size_t)2048 * K2_;      // [4096][128] bf16
    unsigned short* kA_b = qt_b + MK;
    unsigned short* kB_b = kA_b + MK;
    unsigned short* Wqk  = kB_b + MK;                      // [256][2048] bf16
    unsigned short* Pbuf = Wqk + (size_t)256 * H_;         // [64][64][128] bf16
    float* partial  = (float*)(Pbuf + (size_t)64 * 64 * 128);  // [4][4096][256]
    float* rrms_acc = partial + (size_t)4 * 4096 * 256;    // [4096] fp32
    // ws use: 48 MB bf16 GEMM bufs + 3 MB qk + 1 MB W + 1 MB P + 16 MB partial

    prep_all<<<JOBA_BLKS + JOBB_BLKS + JOBC_BLKS, 256, 0, stream>>>(
        x, Wq, Wk, Wog, Wig, Abuf, Wqk, Bbuf, rrms_acc);
    qk_proj_mfma<<<dim3(32, 2, 4), 256, 0, stream>>>(Abuf, Wqk, partial);
    scan_scale_kernel<<<dim3(32, B_, 4), 256, 0, stream>>>(partial, qt_b, kA_b, kB_b);
    p_kernel<<<dim3(32, B_), 256, 0, stream>>>(qt_b, kA_b, kB_b, Pbuf);
    pv_kernel<<<dim3(32, B_, 16), 256, 0, stream>>>(Pbuf, Abuf, rrms_acc);
    out_gemm_mfma<<<dim3(32, 16), 256, 0, stream>>>(Abuf, Bbuf, gw, rrms_acc, out);
}